// Round 1
// baseline (1158.887 us; speedup 1.0000x reference)
//
#include <hip/hip_runtime.h>
#include <math.h>

#define N_ROWS 100000
#define MUL_IN 256
#define MUL_H  64
#define RPW    8            // rows per wave
#define WAVES  4            // waves per block
#define ROWS_PER_BLOCK (RPW * WAVES)

__device__ __forceinline__ float silu_f(float v) {
    return v * (1.0f / (1.0f + __expf(-v)));
}

__global__ __launch_bounds__(WAVES * 64)
void ndr_fp32_kernel(const float* __restrict__ x,
                     const float* __restrict__ w1_s,
                     const float* __restrict__ w1_v,
                     const float* __restrict__ w2_s,
                     const float* __restrict__ w2_v,
                     float* __restrict__ out)
{
    const int lane = threadIdx.x & 63;
    const int wid  = threadIdx.x >> 6;
    const int row0 = (blockIdx.x * WAVES + wid) * RPW;
    if (row0 >= N_ROWS) return;

    // acc_s0[r] = sum_m xs[m] * w1_s[m][lane]          (scalars col = lane)
    // acc_s1[r] = sum_m xs[m] * w1_s[m][64+lane]       (gates col   = lane)
    // acc_vi[r] = sum_m xv[m][i] * w1_v[m][lane]       (h_v[k=lane][i])
    float acc_s0[RPW] = {}, acc_s1[RPW] = {};
    float acc_v0[RPW] = {}, acc_v1[RPW] = {}, acc_v2[RPW] = {};

    const float* xbase = x + (size_t)row0 * 1024;

    for (int m = 0; m < MUL_IN; m += 4) {
        // lane-indexed weight loads: coalesced, L2-resident
        float ws0[4], ws1[4], wv[4];
        #pragma unroll
        for (int t = 0; t < 4; ++t) {
            ws0[t] = w1_s[(m + t) * 128 + lane];
            ws1[t] = w1_s[(m + t) * 128 + 64 + lane];
            wv[t]  = w1_v[(m + t) * 64 + lane];
        }
        #pragma unroll
        for (int r = 0; r < RPW; ++r) {
            const float* xr = xbase + r * 1024;
            // wave-uniform broadcast loads (16B aligned)
            float4 a  = *(const float4*)(xr + m);                 // xs[m..m+3]
            float4 b0 = *(const float4*)(xr + 256 + 3 * m);       // xv flat [3m..3m+3]
            float4 b1 = *(const float4*)(xr + 256 + 3 * m + 4);
            float4 b2 = *(const float4*)(xr + 256 + 3 * m + 8);

            acc_s0[r] = fmaf(a.x, ws0[0], acc_s0[r]);
            acc_s0[r] = fmaf(a.y, ws0[1], acc_s0[r]);
            acc_s0[r] = fmaf(a.z, ws0[2], acc_s0[r]);
            acc_s0[r] = fmaf(a.w, ws0[3], acc_s0[r]);

            acc_s1[r] = fmaf(a.x, ws1[0], acc_s1[r]);
            acc_s1[r] = fmaf(a.y, ws1[1], acc_s1[r]);
            acc_s1[r] = fmaf(a.z, ws1[2], acc_s1[r]);
            acc_s1[r] = fmaf(a.w, ws1[3], acc_s1[r]);

            // xv[m+t][i] = flat[3(m+t)+i]; within b0..b2: idx 3t+i
            acc_v0[r] = fmaf(b0.x, wv[0], acc_v0[r]);   // t0 i0
            acc_v1[r] = fmaf(b0.y, wv[0], acc_v1[r]);   // t0 i1
            acc_v2[r] = fmaf(b0.z, wv[0], acc_v2[r]);   // t0 i2
            acc_v0[r] = fmaf(b0.w, wv[1], acc_v0[r]);   // t1 i0
            acc_v1[r] = fmaf(b1.x, wv[1], acc_v1[r]);   // t1 i1
            acc_v2[r] = fmaf(b1.y, wv[1], acc_v2[r]);   // t1 i2
            acc_v0[r] = fmaf(b1.z, wv[2], acc_v0[r]);   // t2 i0
            acc_v1[r] = fmaf(b1.w, wv[2], acc_v1[r]);   // t2 i1
            acc_v2[r] = fmaf(b2.x, wv[2], acc_v2[r]);   // t2 i2
            acc_v0[r] = fmaf(b2.y, wv[3], acc_v0[r]);   // t3 i0
            acc_v1[r] = fmaf(b2.z, wv[3], acc_v1[r]);   // t3 i1
            acc_v2[r] = fmaf(b2.w, wv[3], acc_v2[r]);   // t3 i2
        }
    }

    // epilogue: silu-gate + second layer (length-64 contraction = wave reduce)
    const float inv_in = 0.0625f;   // 1/sqrt(256)
    const float inv_h  = 0.125f;    // 1/sqrt(64)
    const float w2sv = w2_s[lane];  // k = lane
    const float w2vv = w2_v[lane];

    #pragma unroll
    for (int r = 0; r < RPW; ++r) {
        float hs = acc_s0[r] * inv_in;          // scalars[lane]
        float hg = acc_s1[r] * inv_in;          // gates[lane]
        float g  = silu_f(hg);
        float v0 = silu_f(hs) * w2sv;                    // -> out_s
        float v1 = g * (acc_v0[r] * inv_in) * w2vv;      // -> out_v i=0
        float v2 = g * (acc_v1[r] * inv_in) * w2vv;
        float v3 = g * (acc_v2[r] * inv_in) * w2vv;

        #pragma unroll
        for (int off = 32; off; off >>= 1) {
            v0 += __shfl_xor(v0, off, 64);
            v1 += __shfl_xor(v1, off, 64);
            v2 += __shfl_xor(v2, off, 64);
            v3 += __shfl_xor(v3, off, 64);
        }
        if (lane == 0) {
            float4 o = make_float4(v0 * inv_h, v1 * inv_h, v2 * inv_h, v3 * inv_h);
            *(float4*)(out + (size_t)(row0 + r) * 4) = o;
        }
    }
}

extern "C" void kernel_launch(void* const* d_in, const int* in_sizes, int n_in,
                              void* d_out, int out_size, void* d_ws, size_t ws_size,
                              hipStream_t stream) {
    const float* x    = (const float*)d_in[0];
    const float* w1_s = (const float*)d_in[1];
    const float* w1_v = (const float*)d_in[2];
    const float* w2_s = (const float*)d_in[3];
    const float* w2_v = (const float*)d_in[4];
    float* out = (float*)d_out;

    int blocks = (N_ROWS + ROWS_PER_BLOCK - 1) / ROWS_PER_BLOCK;  // 3125
    ndr_fp32_kernel<<<blocks, WAVES * 64, 0, stream>>>(x, w1_s, w1_v, w2_s, w2_v, out);
}